// Round 1
// baseline (692.083 us; speedup 1.0000x reference)
//
#include <hip/hip_runtime.h>
#include <hip/hip_bf16.h>
#include <math.h>

#define BATCH 512
#define SEQ   256
#define HID   768   // floats per row per source
#define H4    192   // float4 per row per source

// ---------------------------------------------------------------------------
// Kernel 1: effective lengths. Mask rows are prefix-of-ones (arange < len),
// so eff = sum(mask_row); sum==S also covers the reference's L==0 -> S branch.
// One wave (64 lanes) per row; 2*B = 1024 rows.
// ---------------------------------------------------------------------------
__global__ __launch_bounds__(256) void eff_kernel(const int* __restrict__ m1,
                                                  const int* __restrict__ m2,
                                                  int* __restrict__ eff) {
    int gid  = blockIdx.x * 256 + threadIdx.x;
    int row  = gid >> 6;            // global wave id, [0, 1024)
    int lane = gid & 63;
    if (row >= 2 * BATCH) return;
    int src = row >> 9;             // /512
    int b   = row & (BATCH - 1);
    const int* m = (src == 0) ? m1 : m2;
    int sum = 0;
    #pragma unroll
    for (int i = 0; i < SEQ / 64; ++i)
        sum += m[b * SEQ + lane + i * 64];
    #pragma unroll
    for (int off = 32; off > 0; off >>= 1)
        sum += __shfl_down(sum, off, 64);
    if (lane == 0) eff[row] = sum;
}

// ---------------------------------------------------------------------------
// Kernel 2: masked max pooling. One block per (batch, source).
// 192 threads; thread t owns float4 column t (16B/lane, 3072B = one H-row,
// fully coalesced). Only rows s < eff are ever fetched from HBM.
// ---------------------------------------------------------------------------
__global__ __launch_bounds__(192) void pool_kernel(const float* __restrict__ x1,
                                                   const float* __restrict__ x2,
                                                   const int* __restrict__ eff,
                                                   float* __restrict__ p) {
    int blk = blockIdx.x;           // [0, 2*BATCH)
    int src = blk >> 9;
    int b   = blk & (BATCH - 1);
    int e   = eff[src * BATCH + b]; // in [1, 256]
    const float* x = (src == 0) ? x1 : x2;
    int t = threadIdx.x;            // [0, 192)

    const float4* xrow = reinterpret_cast<const float4*>(x + (size_t)b * SEQ * HID) + t;

    float4 acc = make_float4(-INFINITY, -INFINITY, -INFINITY, -INFINITY);
    int s = 0;
    // unroll by 4 rows for load ILP
    for (; s + 4 <= e; s += 4) {
        float4 v0 = xrow[(size_t)(s + 0) * H4];
        float4 v1 = xrow[(size_t)(s + 1) * H4];
        float4 v2 = xrow[(size_t)(s + 2) * H4];
        float4 v3 = xrow[(size_t)(s + 3) * H4];
        acc.x = fmaxf(acc.x, fmaxf(fmaxf(v0.x, v1.x), fmaxf(v2.x, v3.x)));
        acc.y = fmaxf(acc.y, fmaxf(fmaxf(v0.y, v1.y), fmaxf(v2.y, v3.y)));
        acc.z = fmaxf(acc.z, fmaxf(fmaxf(v0.z, v1.z), fmaxf(v2.z, v3.z)));
        acc.w = fmaxf(acc.w, fmaxf(fmaxf(v0.w, v1.w), fmaxf(v2.w, v3.w)));
    }
    for (; s < e; ++s) {
        float4 v = xrow[(size_t)s * H4];
        acc.x = fmaxf(acc.x, v.x);
        acc.y = fmaxf(acc.y, v.y);
        acc.z = fmaxf(acc.z, v.z);
        acc.w = fmaxf(acc.w, v.w);
    }

    float4* prow = reinterpret_cast<float4*>(p + (size_t)b * (2 * HID) + src * HID) + t;
    *prow = acc;
}

// ---------------------------------------------------------------------------
// Kernel 3: out[b][c] = sum_h p[b][h] * W[c][h] + bias[c], C=2, 2H=1536.
// One block per batch row. W (12 KB) stays L2/L1 resident.
// ---------------------------------------------------------------------------
__global__ __launch_bounds__(256) void gemv_kernel(const float* __restrict__ p,
                                                   const float* __restrict__ W,
                                                   const float* __restrict__ bias,
                                                   float* __restrict__ out) {
    int b = blockIdx.x;
    int t = threadIdx.x;
    const float* pr = p + (size_t)b * (2 * HID);
    float a0 = 0.f, a1 = 0.f;
    #pragma unroll
    for (int i = 0; i < (2 * HID) / 256; ++i) {
        int h = t + i * 256;
        float v = pr[h];
        a0 += v * W[h];
        a1 += v * W[2 * HID + h];
    }
    #pragma unroll
    for (int off = 32; off > 0; off >>= 1) {
        a0 += __shfl_down(a0, off, 64);
        a1 += __shfl_down(a1, off, 64);
    }
    __shared__ float s0[4], s1[4];
    int w = t >> 6, lane = t & 63;
    if (lane == 0) { s0[w] = a0; s1[w] = a1; }
    __syncthreads();
    if (t == 0) {
        float r0 = s0[0] + s0[1] + s0[2] + s0[3];
        float r1 = s1[0] + s1[1] + s1[2] + s1[3];
        out[b * 2 + 0] = r0 + bias[0];
        out[b * 2 + 1] = r1 + bias[1];
    }
}

extern "C" void kernel_launch(void* const* d_in, const int* in_sizes, int n_in,
                              void* d_out, int out_size, void* d_ws, size_t ws_size,
                              hipStream_t stream) {
    const float* x1  = (const float*)d_in[0];
    const float* x2  = (const float*)d_in[1];
    const int*   m1  = (const int*)d_in[2];
    const int*   m2  = (const int*)d_in[3];
    const float* W   = (const float*)d_in[4];
    const float* bia = (const float*)d_in[5];
    float* out = (float*)d_out;

    // workspace layout: eff[1024] ints, then p[512][1536] floats (16B aligned)
    int*   eff = (int*)d_ws;
    float* p   = (float*)((char*)d_ws + 8192);

    eff_kernel<<<(2 * BATCH * 64) / 256, 256, 0, stream>>>(m1, m2, eff);
    pool_kernel<<<2 * BATCH, 192, 0, stream>>>(x1, x2, eff, p);
    gemv_kernel<<<BATCH, 256, 0, stream>>>(p, W, bia, out);
}